// Round 1
// baseline (925.671 us; speedup 1.0000x reference)
//
#include <hip/hip_runtime.h>

#define D_MODEL 2048
#define N_EXP   64
#define TOKS    64      // tokens per block
#define KSUP    128     // k per super-step
#define NSUP    (D_MODEL / KSUP)

// ---------------- W transpose: W[64][2048] -> Wt[2048][64] in d_ws ----------
__global__ void transpose_W(const float* __restrict__ W, float* __restrict__ Wt) {
    int o = blockIdx.x * 256 + threadIdx.x;      // o = k*64 + e  (coalesced write)
    int k = o >> 6;
    int e = o & 63;
    Wt[o] = W[e * D_MODEL + k];                  // strided read, W is L2-resident
}

// ---------------- main fused router ----------------------------------------
struct SMem {
    union {
        float Xs[KSUP][TOKS + 1];   // 33.0 KB, col-major x tile, +1 pad breaks write conflicts
        float P[2][N_EXP][TOKS];    // 32 KB reduction scratch (overlay; used after k-loop)
    };
};

__global__ __launch_bounds__(256, 4)
void router_main(const float* __restrict__ x,
                 const float* __restrict__ Wt,
                 const float* __restrict__ bias,
                 float* __restrict__ out,
                 int n_tokens)
{
    __shared__ SMem sm;

    const int tid  = threadIdx.x;
    const int lane = tid & 63;
    const int wave = tid >> 6;
    const int tok0 = blockIdx.x * TOKS;

    float acc[N_EXP];
    #pragma unroll
    for (int e = 0; e < N_EXP; ++e) acc[e] = 0.f;

    for (int s = 0; s < NSUP; ++s) {
        const int ks = s * KSUP;
        __syncthreads();   // previous compute done reading Xs
        // stage 64 tok x 128 k: 2048 float4, 8 per thread, coalesced global reads
        #pragma unroll
        for (int i = 0; i < (TOKS * KSUP / 4) / 256; ++i) {
            int f4  = i * 256 + tid;
            int tok = f4 >> 5;            // 32 float4 per token row
            int c   = f4 & 31;
            const float4 v = *(const float4*)(x + (size_t)(tok0 + tok) * D_MODEL + ks + 4 * c);
            sm.Xs[4*c+0][tok] = v.x;
            sm.Xs[4*c+1][tok] = v.y;
            sm.Xs[4*c+2][tok] = v.z;
            sm.Xs[4*c+3][tok] = v.w;
        }
        __syncthreads();
        // interleaved K-split: this wave handles kk ≡ wave (mod 4)
        for (int j = 0; j < KSUP / 4; ++j) {
            const int kk = 4 * j + wave;
            const float xv = sm.Xs[kk][lane];                       // lane = token, conflict-free
            const float4* w4 = (const float4*)(Wt + (size_t)(ks + kk) * N_EXP);
            #pragma unroll
            for (int e4 = 0; e4 < N_EXP / 4; ++e4) {
                float4 w = w4[e4];                                  // wave-uniform -> s_load
                acc[4*e4+0] = fmaf(w.x, xv, acc[4*e4+0]);
                acc[4*e4+1] = fmaf(w.y, xv, acc[4*e4+1]);
                acc[4*e4+2] = fmaf(w.z, xv, acc[4*e4+2]);
                acc[4*e4+3] = fmaf(w.w, xv, acc[4*e4+3]);
            }
        }
    }

    // ---- cross-wave tree reduction (waves hold k-partials of same 64 tokens)
    __syncthreads();
    if (wave >= 2) {
        float* Pp = &sm.P[wave - 2][0][0];
        #pragma unroll
        for (int e = 0; e < N_EXP; ++e) Pp[e * TOKS + lane] = acc[e];   // contiguous: no conflicts
    }
    __syncthreads();
    if (wave < 2) {
        const float* Pp = &sm.P[wave][0][0];
        #pragma unroll
        for (int e = 0; e < N_EXP; ++e) acc[e] += Pp[e * TOKS + lane];
    }
    __syncthreads();
    if (wave == 1) {
        float* Pp = &sm.P[0][0][0];
        #pragma unroll
        for (int e = 0; e < N_EXP; ++e) Pp[e * TOKS + lane] = acc[e];
    }
    __syncthreads();
    if (wave == 0) {
        const float* Pp = &sm.P[0][0][0];
        #pragma unroll
        for (int e = 0; e < N_EXP; ++e) acc[e] += Pp[e * TOKS + lane] + bias[e];

        // top-2 on logits (exp is monotone -> same ranking as probs);
        // strict '>' ascending scan == torch.topk tie rule (lowest index first)
        float v1 = acc[0]; int i1 = 0;
        float v2 = -3.4e38f; int i2 = 0;
        #pragma unroll
        for (int e = 1; e < N_EXP; ++e) {
            float v  = acc[e];
            bool gt1 = v > v1;
            bool gt2 = v > v2;
            float nv2 = gt1 ? v1 : (gt2 ? v : v2);
            int   ni2 = gt1 ? i1 : (gt2 ? e : i2);
            v2 = nv2; i2 = ni2;
            if (gt1) { v1 = v; i1 = e; }
        }
        float ssum = 0.f;
        #pragma unroll
        for (int e = 0; e < N_EXP; ++e) ssum += __expf(acc[e] - v1);
        float inv = 1.0f / ssum;
        float w1  = inv;                   // exp(v1-v1)/sum
        float w2  = __expf(v2 - v1) * inv;

        int g = tok0 + lane;
        out[2 * g + 0] = (float)i1;        // idx chunk as float32 values
        out[2 * g + 1] = (float)i2;
        float* ow = out + 2 * (size_t)n_tokens;
        ow[2 * g + 0] = w1;
        ow[2 * g + 1] = w2;
    }
}

extern "C" void kernel_launch(void* const* d_in, const int* in_sizes, int n_in,
                              void* d_out, int out_size, void* d_ws, size_t ws_size,
                              hipStream_t stream) {
    const float* x = (const float*)d_in[0];
    const float* W = (const float*)d_in[1];
    const float* b = (const float*)d_in[2];
    float* out = (float*)d_out;
    float* Wt  = (float*)d_ws;                       // 512 KB scratch
    const int n_tokens = in_sizes[0] / D_MODEL;      // 32768

    transpose_W<<<(D_MODEL * N_EXP) / 256, 256, 0, stream>>>(W, Wt);
    router_main<<<n_tokens / TOKS, 256, 0, stream>>>(x, Wt, b, out, n_tokens);
}